// Round 12
// baseline (652.192 us; speedup 1.0000x reference)
//
#include <hip/hip_runtime.h>

typedef unsigned short u16;
typedef __bf16 bf16x8 __attribute__((ext_vector_type(8)));
typedef float  f32x4  __attribute__((ext_vector_type(4)));
typedef unsigned short u16x8 __attribute__((ext_vector_type(8)));

union U8cast { u16x8 u; bf16x8 b; };

#define NB 32
#define NN 4096
#define ND 256
#define NS 11
#define NH 256
#define NM 512

__device__ __forceinline__ u16 f2bf(float f) {
  unsigned u = __float_as_uint(f);
  u += 0x7FFF + ((u >> 16) & 1);      // RNE; inputs are finite
  return (u16)(u >> 16);
}
__device__ __forceinline__ float bf2f(u16 h) {
  return __uint_as_float(((unsigned)h) << 16);
}

// ---------------- fused stats + LN apply -> bf16 normalized copy -----------
__global__ void k_stats_ln(const float* __restrict__ x, const float* __restrict__ sc,
                           const float* __restrict__ of, u16* __restrict__ xbf) {
  int lane = threadIdx.x & 63;
  int wid  = threadIdx.x >> 6;
  int row  = blockIdx.x * 4 + wid;
  float4 v = *(const float4*)(x + (size_t)row * 256 + lane * 4);
  float s1 = v.x + v.y + v.z + v.w;
  float s2 = v.x*v.x + v.y*v.y + v.z*v.z + v.w*v.w;
#pragma unroll
  for (int off = 32; off; off >>= 1) { s1 += __shfl_xor(s1, off); s2 += __shfl_xor(s2, off); }
  float mu = s1 * (1.f/256.f);
  float rs = rsqrtf(s2 * (1.f/256.f) - mu*mu + 1e-5f);
  float4 s4 = *(const float4*)(sc + lane * 4);
  float4 o4 = *(const float4*)(of + lane * 4);
  ushort4 o;
  o.x = f2bf((v.x - mu) * (rs * s4.x) + o4.x);
  o.y = f2bf((v.y - mu) * (rs * s4.y) + o4.y);
  o.z = f2bf((v.z - mu) * (rs * s4.z) + o4.z);
  o.w = f2bf((v.w - mu) * (rs * s4.w) + o4.w);
  *(ushort4*)(xbf + (size_t)row * 256 + lane * 4) = o;
}

// ---------------- Wk -> transposed bf16 wT[256][256] (LDS transpose) -------
__global__ __launch_bounds__(256)
void k_cvt_w(const float* __restrict__ Wk, u16* __restrict__ wT) {
  __shared__ float Lt[64][65];
  int bx = blockIdx.x;              // 16 blocks: 4 k-tiles x 4 c-tiles
  int kt = bx & 3, ct = bx >> 2;
  int k0 = kt * 64, c0 = ct * 64;
  int t = threadIdx.x;
  int kr = t >> 2, part = t & 3;
  const float* sp = Wk + (size_t)(k0 + kr) * 256 + c0 + part * 16;
#pragma unroll
  for (int g = 0; g < 4; ++g) {
    float4 v = *(const float4*)(sp + g * 4);
    Lt[kr][part*16 + g*4 + 0] = v.x;
    Lt[kr][part*16 + g*4 + 1] = v.y;
    Lt[kr][part*16 + g*4 + 2] = v.z;
    Lt[kr][part*16 + g*4 + 3] = v.w;
  }
  __syncthreads();
  int cr = t >> 2;
  u16* wp = wT + (size_t)(c0 + cr) * 256 + k0 + part * 16;
#pragma unroll
  for (int g = 0; g < 2; ++g) {
    u16x8 o;
#pragma unroll
    for (int j = 0; j < 8; ++j) o[j] = f2bf(Lt[part*16 + g*8 + j][cr]);
    *(u16x8*)(wp + g * 8) = o;
  }
}

// ---------------- M = Wq @ Wk^T  (bf16, folds kf out of the pipeline) ------
__global__ __launch_bounds__(256)
void k_mk(const float* __restrict__ Wq, const u16* __restrict__ wT,
          u16* __restrict__ Mb) {
  __shared__ float xn[256];
  __shared__ float part[8][256];
  int e = blockIdx.x, t = threadIdx.x;
  xn[t] = Wq[e*256 + t];
  __syncthreads();
  int tc = t & 31, kg = t >> 5;
  float a[8] = {};
#pragma unroll 8
  for (int kk = 0; kk < 32; ++kk) {
    int k = kg*32 + kk;
    float xv = xn[k];
    u16x8 wv = *(const u16x8*)(wT + k*256 + tc*8);
#pragma unroll
    for (int j = 0; j < 8; ++j) a[j] += xv * bf2f(wv[j]);
  }
  *(float4*)&part[kg][tc*8]     = make_float4(a[0], a[1], a[2], a[3]);
  *(float4*)&part[kg][tc*8 + 4] = make_float4(a[4], a[5], a[6], a[7]);
  __syncthreads();
  float s = 0.f;
#pragma unroll
  for (int g = 0; g < 8; ++g) s += part[g][t];
  Mb[e*256 + t] = f2bf(s);
}

// ---------------- Wvi = Wv @ gru_wi  (f32 inputs -> bf16, 256x768) ---------
__global__ __launch_bounds__(384)
void k_wvi(const float* __restrict__ Wv, const float* __restrict__ wi,
           u16* __restrict__ wvib) {
  __shared__ float xn[256];
  __shared__ float part[4][768];
  int d = blockIdx.x, t = threadIdx.x;
  if (t < 256) xn[t] = Wv[d*256 + t];
  __syncthreads();
  int tc = t % 96, kg = t / 96;
  float a[8] = {};
#pragma unroll 4
  for (int kk = 0; kk < 64; ++kk) {
    int k = kg*64 + kk;
    float xv = xn[k];
    float4 w0 = *(const float4*)(wi + (size_t)k*768 + tc*8);
    float4 w1 = *(const float4*)(wi + (size_t)k*768 + tc*8 + 4);
    a[0] += xv * w0.x; a[1] += xv * w0.y; a[2] += xv * w0.z; a[3] += xv * w0.w;
    a[4] += xv * w1.x; a[5] += xv * w1.y; a[6] += xv * w1.z; a[7] += xv * w1.w;
  }
  *(float4*)&part[kg][tc*8]     = make_float4(a[0], a[1], a[2], a[3]);
  *(float4*)&part[kg][tc*8 + 4] = make_float4(a[4], a[5], a[6], a[7]);
  __syncthreads();
#pragma unroll
  for (int c = t; c < 768; c += 384) {
    float s = part[0][c] + part[1][c] + part[2][c] + part[3][c];
    wvib[d*768 + c] = f2bf(s);
  }
}

// ---------------- weights -> bf16 + slots init (merged) --------------------
__global__ void k_cvt_all(const float* __restrict__ wh, const float* __restrict__ w1,
                          const float* __restrict__ w2,
                          const float* __restrict__ noise, const float* __restrict__ smu,
                          const float* __restrict__ sls,
                          u16* __restrict__ whb, u16* __restrict__ w1b,
                          u16* __restrict__ w2b, float* __restrict__ slots) {
  int idx = blockIdx.x * 256 + threadIdx.x;
  if      (idx < 196608) whb[idx]          = f2bf(wh[idx]);
  else if (idx < 327680) w1b[idx - 196608] = f2bf(w1[idx - 196608]);
  else if (idx < 458752) w2b[idx - 327680] = f2bf(w2[idx - 327680]);
  else {
    int i = idx - 458752;                 // 90112 slot elements
    int c = i & 255;
    slots[i] = smu[c] + expf(sls[c]) * noise[i];
  }
}

// ---------------- qk2 = LN(slots) @ M * H^-0.5 (pre-loop) ------------------
__global__ __launch_bounds__(256)
void k_q_ln(const float* __restrict__ slots, const float* __restrict__ sc,
            const float* __restrict__ of, const u16* __restrict__ Mb,
            float* __restrict__ qk2) {
  __shared__ float xn[256];
  __shared__ float red[8];
  __shared__ float part[8][256];
  int row = blockIdx.x, t = threadIdx.x;
  float v = slots[row*256 + t];
  float s1 = v, s2 = v*v;
#pragma unroll
  for (int off = 32; off; off >>= 1) { s1 += __shfl_xor(s1, off); s2 += __shfl_xor(s2, off); }
  int w = t >> 6;
  if ((t & 63) == 0) { red[w*2] = s1; red[w*2+1] = s2; }
  __syncthreads();
  float a1 = red[0] + red[2] + red[4] + red[6];
  float a2 = red[1] + red[3] + red[5] + red[7];
  float mu = a1 * (1.f/256.f);
  float rs = rsqrtf(a2 * (1.f/256.f) - mu*mu + 1e-5f);
  xn[t] = (v - mu) * rs * sc[t] + of[t];
  __syncthreads();
  int tc = t & 31, kg = t >> 5;
  float a[8] = {};
#pragma unroll 8
  for (int kk = 0; kk < 32; ++kk) {
    int k = kg*32 + kk;
    float xv = xn[k];
    u16x8 wv = *(const u16x8*)(Mb + k*256 + tc*8);
#pragma unroll
    for (int j = 0; j < 8; ++j) a[j] += xv * bf2f(wv[j]);
  }
  *(float4*)&part[kg][tc*8]     = make_float4(a[0], a[1], a[2], a[3]);
  *(float4*)&part[kg][tc*8 + 4] = make_float4(a[4], a[5], a[6], a[7]);
  __syncthreads();
  float s = 0.f;
#pragma unroll
  for (int g = 0; g < 8; ++g) s += part[g][t];
  qk2[row*256 + t] = s * 0.0625f;
}

// ---------------- FUSED attn (round-11 proven, unchanged) ------------------
__global__ __launch_bounds__(256)
void k_attn_up(const u16* __restrict__ xbf, const float* __restrict__ qg,
               float* __restrict__ upart, float* __restrict__ cpart) {
  __shared__ __align__(16) u16 vfL[64][256];
  __shared__ __align__(16) u16 qTL[16][264];
  __shared__ __align__(16) u16 PTL[16][72];
  __shared__ float Lg[64][17];
  __shared__ float csw[4][12];
  int t = threadIdx.x;
  int b = blockIdx.y;
  int bx = blockIdx.x;
  int nb0 = bx * 256;
  int lane = t & 63, w = t >> 6;
  int fr = lane & 15, kq = lane >> 4;

#pragma unroll
  for (int i = t; i < 512; i += 256) {
    int s = i >> 5, k0 = (i & 31) * 8;
    u16x8 o;
    if (s < 11) {
      const float* qp = qg + (size_t)b*2816 + s*256 + k0;
#pragma unroll
      for (int j = 0; j < 8; ++j) o[j] = f2bf(qp[j]);
    } else {
#pragma unroll
      for (int j = 0; j < 8; ++j) o[j] = 0;
    }
    *(u16x8*)&qTL[s][k0] = o;
  }
  for (int i = t; i < 16*72; i += 256) ((u16*)PTL)[i] = 0;

  f32x4 accU[4] = {};
  float cs0 = 0.f, cs1 = 0.f, cs2 = 0.f;
  int rS = t >> 2, g4 = t & 3;
  int j32  = t & 31;              // 16B slot index within a row
  int nsub = t >> 5;              // == n&7 for the rows this thread fills
  int js   = (j32 ^ nsub) * 8;    // swizzled u16 column
  int hc   = j32 * 8;

  for (int c = 0; c < 4; ++c) {
    int n0 = nb0 + c*64;
    __syncthreads();
    {
#pragma unroll
      for (int nr = 0; nr < 8; ++nr) {
        int n = nr*8 + nsub;
        size_t base = ((size_t)b*4096 + n0 + n) * 256;
        u16x8 kvk = *(const u16x8*)(xbf + base + hc);
        *(u16x8*)&vfL[n][js] = kvk;
      }
    }
    __syncthreads();
    {
      f32x4 aL = {};
      int n = w*16 + fr;
#pragma unroll
      for (int kc = 0; kc < 256; kc += 32) {
        bf16x8 af = *(const bf16x8*)&vfL[n][((kc/8 + kq) ^ (fr & 7)) * 8];
        bf16x8 bq = *(const bf16x8*)&qTL[fr][kc + kq*8];
        aL = __builtin_amdgcn_mfma_f32_16x16x32_bf16(af, bq, aL, 0, 0, 0);
      }
#pragma unroll
      for (int r = 0; r < 4; ++r)
        Lg[w*16 + kq*4 + r][fr] = aL[r];
    }
    __syncthreads();
    { // wave-parallel softmax: 4 threads per row, slots split 4+4+3
      float p0 = Lg[rS][g4];
      float p1 = Lg[rS][g4 + 4];
      float p2 = (g4 < 3) ? Lg[rS][g4 + 8] : -1e30f;
      float m = fmaxf(fmaxf(p0, p1), p2);
      m = fmaxf(m, __shfl_xor(m, 1));
      m = fmaxf(m, __shfl_xor(m, 2));
      p0 = __expf(p0 - m); p1 = __expf(p1 - m);
      p2 = (g4 < 3) ? __expf(p2 - m) : 0.f;
      float Z = p0 + p1 + p2;
      Z += __shfl_xor(Z, 1);
      Z += __shfl_xor(Z, 2);
      float iz = 1.f / Z;
      u16 b0 = f2bf(p0*iz + 1e-8f);
      u16 b1 = f2bf(p1*iz + 1e-8f);
      PTL[g4][rS]     = b0;  cs0 += bf2f(b0);
      PTL[g4 + 4][rS] = b1;  cs1 += bf2f(b1);
      if (g4 < 3) {
        u16 b2 = f2bf(p2*iz + 1e-8f);
        PTL[g4 + 8][rS] = b2;  cs2 += bf2f(b2);
      }
    }
    __syncthreads();
#pragma unroll
    for (int ht = 0; ht < 4; ++ht) {
      int h = w*64 + ht*16 + fr;
      int h3 = h >> 3, h7 = h & 7;
#pragma unroll
      for (int kc = 0; kc < 64; kc += 32) {
        bf16x8 aP = *(const bf16x8*)&PTL[fr][kc + kq*8];
        U8cast bv;
#pragma unroll
        for (int j = 0; j < 8; ++j) {
          int k = kc + kq*8 + j;          // k&7 == j
          bv.u[j] = vfL[k][((h3 ^ j) << 3) | h7];
        }
        accU[ht] = __builtin_amdgcn_mfma_f32_16x16x32_bf16(aP, bv.b, accU[ht], 0, 0, 0);
      }
    }
  }
  // ---- epilogue: plain stores of the block's full partial tile ----
  {
    size_t ub = ((size_t)bx*352 + (size_t)b*11) * 256;
#pragma unroll
    for (int ht = 0; ht < 4; ++ht) {
      int h = w*64 + ht*16 + fr;
#pragma unroll
      for (int r = 0; r < 4; ++r) {
        int s = kq*4 + r;
        if (s < 11)
          upart[ub + (size_t)s*256 + h] = accU[ht][r];
      }
    }
  }
  { // block colsum: intra-wave butterfly, cross-wave LDS reduce, one store
#pragma unroll
    for (int off = 4; off < 64; off <<= 1) {
      cs0 += __shfl_xor(cs0, off);
      cs1 += __shfl_xor(cs1, off);
      cs2 += __shfl_xor(cs2, off);
    }
    if (lane < 4) { csw[w][lane] = cs0; csw[w][lane + 4] = cs1; }
    if (lane < 3) { csw[w][lane + 8] = cs2; }
    __syncthreads();
    if (t < 11)
      cpart[(size_t)bx*512 + b*16 + t] =
          csw[0][t] + csw[1][t] + csw[2][t] + csw[3][t];
  }
}

// ---------------- GRU with fused gx prologue -------------------------------
// Prologue (round-5 phase-0/1 proven bodies, adapted to privatized partials):
// xnAll = (SUM_p upart)/(SUM_p cpart) for this batch's 11 rows, then
// gxL[11][768] = xnAll @ Wvi entirely in LDS. Then the round-6 proven
// 11-step body, reading gx from LDS instead of global. Removes the k_gx
// dispatch + gap and the gx global round-trip.
__global__ __launch_bounds__(512)
void k_gru(const float* __restrict__ upart, const float* __restrict__ cpart,
           const u16* __restrict__ wvib, const u16* __restrict__ whb,
           const float* __restrict__ gb, float* __restrict__ slots) {
  __shared__ float xnAll[11][256];
  __shared__ float gxL[11][768];
  __shared__ float h[256], rh[256], zv[256];
  __shared__ float part[4096];
  __shared__ float invcs[11];
  int b = blockIdx.x, t = threadIdx.x;
  int row0 = b * 11;

  // ---- prologue A: reduce partials -> normalized updates in LDS ----
  if (t < 11) {
    float cs = 0.f;
#pragma unroll
    for (int p = 0; p < 16; ++p) cs += cpart[(size_t)p*512 + b*16 + t];
    invcs[t] = 1.f / cs;
  }
  if (t < 256) h[t] = 0.f;
  __syncthreads();
  for (int i = t; i < 2816; i += 512) {
    int r = i >> 8, c = i & 255;
    float s = 0.f;
#pragma unroll
    for (int p = 0; p < 16; ++p)
      s += upart[((size_t)p*352 + row0 + r)*256 + c];
    xnAll[r][c] = s * invcs[r];
  }
  __syncthreads();

  // ---- prologue B: gxL = xnAll @ Wvi (round-5 phase-1 proven body) ----
  for (int g = t; g < 1056; g += 512) {
    int r = g / 96, c8 = g % 96;
    const float* xr = xnAll[r];
    float a[8] = {};
#pragma unroll 4
    for (int k = 0; k < 256; ++k) {
      float xv = xr[k];
      u16x8 wv = *(const u16x8*)(wvib + (size_t)k*768 + c8*8);
#pragma unroll
      for (int j = 0; j < 8; ++j) a[j] += xv * bf2f(wv[j]);
    }
#pragma unroll
    for (int j = 0; j < 8; ++j) gxL[r][c8*8 + j] = a[j];
  }
  __syncthreads();

  // ---- 11-step recurrence (round-6 proven body; gx from LDS) ----
  for (int step = 0; step < 11; ++step) {
    {
      int tc = t & 63, kg = t >> 6;
      float a[8] = {};
#pragma unroll 8
      for (int kk = 0; kk < 32; ++kk) {
        int k = kg*32 + kk;
        float xv = h[k];
        u16x8 wv = *(const u16x8*)(whb + k*768 + tc*8);
#pragma unroll
        for (int j = 0; j < 8; ++j) a[j] += xv * bf2f(wv[j]);
      }
      *(float4*)&part[kg*512 + tc*8]     = make_float4(a[0], a[1], a[2], a[3]);
      *(float4*)&part[kg*512 + tc*8 + 4] = make_float4(a[4], a[5], a[6], a[7]);
    }
    __syncthreads();
    {
      int c = t;
      float s = gxL[step][c] + gb[c];
#pragma unroll
      for (int g = 0; g < 8; ++g) s += part[g*512 + c];
      float sg = 1.f / (1.f + __expf(-s));
      if (c < 256) zv[c] = sg;
      else         rh[c - 256] = sg * h[c - 256];
    }
    __syncthreads();
    {
      int tc = t & 31, kg = t >> 5;
      float a[8] = {};
#pragma unroll 8
      for (int kk = 0; kk < 16; ++kk) {
        int k = kg*16 + kk;
        float xv = rh[k];
        u16x8 wv = *(const u16x8*)(whb + k*768 + 512 + tc*8);
#pragma unroll
        for (int j = 0; j < 8; ++j) a[j] += xv * bf2f(wv[j]);
      }
      *(float4*)&part[kg*256 + tc*8]     = make_float4(a[0], a[1], a[2], a[3]);
      *(float4*)&part[kg*256 + tc*8 + 4] = make_float4(a[4], a[5], a[6], a[7]);
    }
    __syncthreads();
    if (t < 256) {
      int c = t;
      float s = gxL[step][512 + c] + gb[512 + c];
#pragma unroll
      for (int g = 0; g < 16; ++g) s += part[g*256 + c];
      float av = tanhf(s);
      float hn = (1.f - zv[c])*h[c] + zv[c]*av;
      h[c] = hn;
      slots[row0*256 + step*256 + c] = hn;
    }
    __syncthreads();
  }
}

// ---------------- MLP + fused next-iter q_ln (round-8 proven) --------------
__global__ __launch_bounds__(256)
void k_mlp(float* __restrict__ slots, const float* __restrict__ sc,
           const float* __restrict__ of, const u16* __restrict__ w1b,
           const float* __restrict__ b1, const u16* __restrict__ w2b,
           const float* __restrict__ b2,
           const float* __restrict__ sls_, const float* __restrict__ slo,
           const u16* __restrict__ Mb, float* __restrict__ qk2,
           float* __restrict__ out2) {
  __shared__ float xn[256];
  __shared__ float hid[512];
  __shared__ float red[8];
  __shared__ float part[2048];
  int row = blockIdx.x, t = threadIdx.x;
  float v = slots[row*256 + t];
  float s1 = v, s2 = v*v;
#pragma unroll
  for (int off = 32; off; off >>= 1) { s1 += __shfl_xor(s1, off); s2 += __shfl_xor(s2, off); }
  int w = t >> 6;
  if ((t & 63) == 0) { red[w*2] = s1; red[w*2+1] = s2; }
  __syncthreads();
  float a1s = red[0] + red[2] + red[4] + red[6];
  float a2s = red[1] + red[3] + red[5] + red[7];
  float mu = a1s * (1.f/256.f);
  float rs = rsqrtf(a2s * (1.f/256.f) - mu*mu + 1e-5f);
  xn[t] = (v - mu) * rs * sc[t] + of[t];
  __syncthreads();
  {
    int tc = t & 63, kg = t >> 6;
    float a[8] = {};
#pragma unroll 4
    for (int kk = 0; kk < 64; ++kk) {
      int k = kg*64 + kk;
      float xv = xn[k];
      u16x8 wv = *(const u16x8*)(w1b + k*512 + tc*8);
#pragma unroll
      for (int j = 0; j < 8; ++j) a[j] += xv * bf2f(wv[j]);
    }
    *(float4*)&part[kg*512 + tc*8]     = make_float4(a[0], a[1], a[2], a[3]);
    *(float4*)&part[kg*512 + tc*8 + 4] = make_float4(a[4], a[5], a[6], a[7]);
  }
  __syncthreads();
#pragma unroll
  for (int c = t; c < 512; c += 256) {
    float s = b1[c];
#pragma unroll
    for (int g = 0; g < 4; ++g) s += part[g*512 + c];
    hid[c] = fmaxf(s, 0.f);
  }
  __syncthreads();
  {
    int tc = t & 31, kg = t >> 5;
    float a[8] = {};
#pragma unroll 4
    for (int kk = 0; kk < 64; ++kk) {
      int k = kg*64 + kk;
      float xv = hid[k];
      u16x8 wv = *(const u16x8*)(w2b + k*256 + tc*8);
#pragma unroll
      for (int j = 0; j < 8; ++j) a[j] += xv * bf2f(wv[j]);
    }
    *(float4*)&part[kg*256 + tc*8]     = make_float4(a[0], a[1], a[2], a[3]);
    *(float4*)&part[kg*256 + tc*8 + 4] = make_float4(a[4], a[5], a[6], a[7]);
  }
  __syncthreads();
  float snew;
  {
    float s = v + b2[t];
#pragma unroll
    for (int g = 0; g < 8; ++g) s += part[g*256 + t];
    snew = s;
    slots[row*256 + t] = snew;
    if (out2) out2[row*256 + t] = snew;
  }
  if (!qk2) return;
  // fused q_ln: qk2 = LN_slots(snew) @ Mb * H^-0.5
  float q1 = snew, q2 = snew*snew;
#pragma unroll
  for (int off = 32; off; off >>= 1) { q1 += __shfl_xor(q1, off); q2 += __shfl_xor(q2, off); }
  __syncthreads();                       // all prior red/part reads complete
  if ((t & 63) == 0) { red[w*2] = q1; red[w*2+1] = q2; }
  __syncthreads();
  {
    float b1v = red[0] + red[2] + red[4] + red[6];
    float b2v = red[1] + red[3] + red[5] + red[7];
    float mu2 = b1v * (1.f/256.f);
    float rs2 = rsqrtf(b2v * (1.f/256.f) - mu2*mu2 + 1e-5f);
    xn[t] = (snew - mu2) * rs2 * sls_[t] + slo[t];
  }
  __syncthreads();
  {
    int tc = t & 31, kg = t >> 5;
    float a[8] = {};
#pragma unroll 8
    for (int kk = 0; kk < 32; ++kk) {
      int k = kg*32 + kk;
      float xv = xn[k];
      u16x8 wv = *(const u16x8*)(Mb + k*256 + tc*8);
#pragma unroll
      for (int j = 0; j < 8; ++j) a[j] += xv * bf2f(wv[j]);
    }
    *(float4*)&part[kg*256 + tc*8]     = make_float4(a[0], a[1], a[2], a[3]);
    *(float4*)&part[kg*256 + tc*8 + 4] = make_float4(a[4], a[5], a[6], a[7]);
  }
  __syncthreads();
  {
    float s = 0.f;
#pragma unroll
    for (int g = 0; g < 8; ++g) s += part[g*256 + t];
    qk2[row*256 + t] = s * 0.0625f;
  }
}

extern "C" void kernel_launch(void* const* d_in, const int* in_sizes, int n_in,
                              void* d_out, int out_size, void* d_ws, size_t ws_size,
                              hipStream_t stream) {
  (void)in_sizes; (void)n_in; (void)out_size; (void)ws_size;
  const float* inputs = (const float*)d_in[0];
  const float* noise  = (const float*)d_in[1];
  const float* lnin_s = (const float*)d_in[2];
  const float* lnin_o = (const float*)d_in[3];
  const float* lnsl_s = (const float*)d_in[4];
  const float* lnsl_o = (const float*)d_in[5];
  const float* lnml_s = (const float*)d_in[6];
  const float* lnml_o = (const float*)d_in[7];
  const float* smu    = (const float*)d_in[8];
  const float* sls    = (const float*)d_in[9];
  const float* Wq     = (const float*)d_in[10];
  const float* Wk     = (const float*)d_in[11];
  const float* Wv     = (const float*)d_in[12];
  const float* gwi    = (const float*)d_in[13];
  const float* gwh    = (const float*)d_in[14];
  const float* gb     = (const float*)d_in[15];
  const float* w1     = (const float*)d_in[16];
  const float* b1     = (const float*)d_in[17];
  const float* w2     = (const float*)d_in[18];
  const float* b2     = (const float*)d_in[19];

  // ---- workspace layout (512 MiB arena). High-water ~216.2 MB. ------------
  char* ws = (char*)d_ws;
  u16*    wT      = (u16*)(ws + 134217728);              // 131,072 B (Wk^T bf16)
  float*  qk2     = (float*)(ws + 135000064);            // 360,448 B
  float*  slots   = (float*)(ws + 139984896);            // 360,448 B
  u16*    Mb      = (u16*)(ws + 141789184);              // 131,072 B (Wq@Wk^T bf16)
  u16*    wvib    = (u16*)(ws + 141920256);              // 393,216 B (Wv@gru_wi bf16)
  u16*    whb     = (u16*)(ws + 142313472);
  u16*    w1b     = (u16*)(ws + 142706688);
  u16*    w2b     = (u16*)(ws + 142968832);
  u16*    xbf     = (u16*)(ws + 143230976);              // 67,108,864 B normalized bf16 x
  float*  upart   = (float*)(ws + 210339840);            // 5,767,168 B [16][352][256]
  float*  cpart   = (float*)(ws + 216107008);            // 32,768 B   [16][512]

  k_stats_ln <<<32768, 256, 0, stream>>>(inputs, lnin_s, lnin_o, xbf);
  k_cvt_w    <<<16,    256, 0, stream>>>(Wk, wT);
  k_mk       <<<256,   256, 0, stream>>>(Wq, wT, Mb);
  k_wvi      <<<256,   384, 0, stream>>>(Wv, gwi, wvib);
  k_cvt_all  <<<2144,  256, 0, stream>>>(gwh, w1, w2, noise, smu, sls,
                                         whb, w1b, w2b, slots);
  k_q_ln     <<<352,   256, 0, stream>>>(slots, lnsl_s, lnsl_o, Mb, qk2);

  for (int it = 0; it < 3; ++it) {
    k_attn_up <<<dim3(16, 32), 256, 0, stream>>>(xbf, qk2, upart, cpart);
    k_gru     <<<32,  512, 0, stream>>>(upart, cpart, wvib, whb, gb, slots);
    k_mlp     <<<352, 256, 0, stream>>>(slots, lnml_s, lnml_o, w1b, b1, w2b, b2,
                                        lnsl_s, lnsl_o, Mb,
                                        (it < 2) ? qk2 : nullptr,
                                        (it == 2) ? (float*)d_out : nullptr);
  }
}

// Round 13
// 528.163 us; speedup vs baseline: 1.2348x; 1.2348x over previous
//
#include <hip/hip_runtime.h>

typedef unsigned short u16;
typedef __bf16 bf16x8 __attribute__((ext_vector_type(8)));
typedef float  f32x4  __attribute__((ext_vector_type(4)));
typedef unsigned short u16x8 __attribute__((ext_vector_type(8)));

union U8cast { u16x8 u; bf16x8 b; };

#define NB 32
#define NN 4096
#define ND 256
#define NS 11
#define NH 256
#define NM 512

__device__ __forceinline__ u16 f2bf(float f) {
  unsigned u = __float_as_uint(f);
  u += 0x7FFF + ((u >> 16) & 1);      // RNE; inputs are finite
  return (u16)(u >> 16);
}
__device__ __forceinline__ float bf2f(u16 h) {
  return __uint_as_float(((unsigned)h) << 16);
}

// ---------------- fused stats + LN apply -> bf16 normalized copy -----------
__global__ void k_stats_ln(const float* __restrict__ x, const float* __restrict__ sc,
                           const float* __restrict__ of, u16* __restrict__ xbf) {
  int lane = threadIdx.x & 63;
  int wid  = threadIdx.x >> 6;
  int row  = blockIdx.x * 4 + wid;
  float4 v = *(const float4*)(x + (size_t)row * 256 + lane * 4);
  float s1 = v.x + v.y + v.z + v.w;
  float s2 = v.x*v.x + v.y*v.y + v.z*v.z + v.w*v.w;
#pragma unroll
  for (int off = 32; off; off >>= 1) { s1 += __shfl_xor(s1, off); s2 += __shfl_xor(s2, off); }
  float mu = s1 * (1.f/256.f);
  float rs = rsqrtf(s2 * (1.f/256.f) - mu*mu + 1e-5f);
  float4 s4 = *(const float4*)(sc + lane * 4);
  float4 o4 = *(const float4*)(of + lane * 4);
  ushort4 o;
  o.x = f2bf((v.x - mu) * (rs * s4.x) + o4.x);
  o.y = f2bf((v.y - mu) * (rs * s4.y) + o4.y);
  o.z = f2bf((v.z - mu) * (rs * s4.z) + o4.z);
  o.w = f2bf((v.w - mu) * (rs * s4.w) + o4.w);
  *(ushort4*)(xbf + (size_t)row * 256 + lane * 4) = o;
}

// ---------------- Wk -> transposed bf16 wT[256][256] (LDS transpose) -------
__global__ __launch_bounds__(256)
void k_cvt_w(const float* __restrict__ Wk, u16* __restrict__ wT) {
  __shared__ float Lt[64][65];
  int bx = blockIdx.x;              // 16 blocks: 4 k-tiles x 4 c-tiles
  int kt = bx & 3, ct = bx >> 2;
  int k0 = kt * 64, c0 = ct * 64;
  int t = threadIdx.x;
  int kr = t >> 2, part = t & 3;
  const float* sp = Wk + (size_t)(k0 + kr) * 256 + c0 + part * 16;
#pragma unroll
  for (int g = 0; g < 4; ++g) {
    float4 v = *(const float4*)(sp + g * 4);
    Lt[kr][part*16 + g*4 + 0] = v.x;
    Lt[kr][part*16 + g*4 + 1] = v.y;
    Lt[kr][part*16 + g*4 + 2] = v.z;
    Lt[kr][part*16 + g*4 + 3] = v.w;
  }
  __syncthreads();
  int cr = t >> 2;
  u16* wp = wT + (size_t)(c0 + cr) * 256 + k0 + part * 16;
#pragma unroll
  for (int g = 0; g < 2; ++g) {
    u16x8 o;
#pragma unroll
    for (int j = 0; j < 8; ++j) o[j] = f2bf(Lt[part*16 + g*8 + j][cr]);
    *(u16x8*)(wp + g * 8) = o;
  }
}

// ---------------- M = Wq @ Wk^T  (bf16, folds kf out of the pipeline) ------
__global__ __launch_bounds__(256)
void k_mk(const float* __restrict__ Wq, const u16* __restrict__ wT,
          u16* __restrict__ Mb) {
  __shared__ float xn[256];
  __shared__ float part[8][256];
  int e = blockIdx.x, t = threadIdx.x;
  xn[t] = Wq[e*256 + t];
  __syncthreads();
  int tc = t & 31, kg = t >> 5;
  float a[8] = {};
#pragma unroll 8
  for (int kk = 0; kk < 32; ++kk) {
    int k = kg*32 + kk;
    float xv = xn[k];
    u16x8 wv = *(const u16x8*)(wT + k*256 + tc*8);
#pragma unroll
    for (int j = 0; j < 8; ++j) a[j] += xv * bf2f(wv[j]);
  }
  *(float4*)&part[kg][tc*8]     = make_float4(a[0], a[1], a[2], a[3]);
  *(float4*)&part[kg][tc*8 + 4] = make_float4(a[4], a[5], a[6], a[7]);
  __syncthreads();
  float s = 0.f;
#pragma unroll
  for (int g = 0; g < 8; ++g) s += part[g][t];
  Mb[e*256 + t] = f2bf(s);
}

// ---------------- Wvi = Wv @ gru_wi  (f32 inputs -> bf16, 256x768) ---------
__global__ __launch_bounds__(384)
void k_wvi(const float* __restrict__ Wv, const float* __restrict__ wi,
           u16* __restrict__ wvib) {
  __shared__ float xn[256];
  __shared__ float part[4][768];
  int d = blockIdx.x, t = threadIdx.x;
  if (t < 256) xn[t] = Wv[d*256 + t];
  __syncthreads();
  int tc = t % 96, kg = t / 96;
  float a[8] = {};
#pragma unroll 4
  for (int kk = 0; kk < 64; ++kk) {
    int k = kg*64 + kk;
    float xv = xn[k];
    float4 w0 = *(const float4*)(wi + (size_t)k*768 + tc*8);
    float4 w1 = *(const float4*)(wi + (size_t)k*768 + tc*8 + 4);
    a[0] += xv * w0.x; a[1] += xv * w0.y; a[2] += xv * w0.z; a[3] += xv * w0.w;
    a[4] += xv * w1.x; a[5] += xv * w1.y; a[6] += xv * w1.z; a[7] += xv * w1.w;
  }
  *(float4*)&part[kg][tc*8]     = make_float4(a[0], a[1], a[2], a[3]);
  *(float4*)&part[kg][tc*8 + 4] = make_float4(a[4], a[5], a[6], a[7]);
  __syncthreads();
#pragma unroll
  for (int c = t; c < 768; c += 384) {
    float s = part[0][c] + part[1][c] + part[2][c] + part[3][c];
    wvib[d*768 + c] = f2bf(s);
  }
}

// ---------------- weights -> bf16 + slots init (merged) --------------------
__global__ void k_cvt_all(const float* __restrict__ wh, const float* __restrict__ w1,
                          const float* __restrict__ w2,
                          const float* __restrict__ noise, const float* __restrict__ smu,
                          const float* __restrict__ sls,
                          u16* __restrict__ whb, u16* __restrict__ w1b,
                          u16* __restrict__ w2b, float* __restrict__ slots) {
  int idx = blockIdx.x * 256 + threadIdx.x;
  if      (idx < 196608) whb[idx]          = f2bf(wh[idx]);
  else if (idx < 327680) w1b[idx - 196608] = f2bf(w1[idx - 196608]);
  else if (idx < 458752) w2b[idx - 327680] = f2bf(w2[idx - 327680]);
  else {
    int i = idx - 458752;                 // 90112 slot elements
    int c = i & 255;
    slots[i] = smu[c] + expf(sls[c]) * noise[i];
  }
}

// ---------------- qk2 = LN(slots) @ M * H^-0.5 (pre-loop) ------------------
__global__ __launch_bounds__(256)
void k_q_ln(const float* __restrict__ slots, const float* __restrict__ sc,
            const float* __restrict__ of, const u16* __restrict__ Mb,
            float* __restrict__ qk2) {
  __shared__ float xn[256];
  __shared__ float red[8];
  __shared__ float part[8][256];
  int row = blockIdx.x, t = threadIdx.x;
  float v = slots[row*256 + t];
  float s1 = v, s2 = v*v;
#pragma unroll
  for (int off = 32; off; off >>= 1) { s1 += __shfl_xor(s1, off); s2 += __shfl_xor(s2, off); }
  int w = t >> 6;
  if ((t & 63) == 0) { red[w*2] = s1; red[w*2+1] = s2; }
  __syncthreads();
  float a1 = red[0] + red[2] + red[4] + red[6];
  float a2 = red[1] + red[3] + red[5] + red[7];
  float mu = a1 * (1.f/256.f);
  float rs = rsqrtf(a2 * (1.f/256.f) - mu*mu + 1e-5f);
  xn[t] = (v - mu) * rs * sc[t] + of[t];
  __syncthreads();
  int tc = t & 31, kg = t >> 5;
  float a[8] = {};
#pragma unroll 8
  for (int kk = 0; kk < 32; ++kk) {
    int k = kg*32 + kk;
    float xv = xn[k];
    u16x8 wv = *(const u16x8*)(Mb + k*256 + tc*8);
#pragma unroll
    for (int j = 0; j < 8; ++j) a[j] += xv * bf2f(wv[j]);
  }
  *(float4*)&part[kg][tc*8]     = make_float4(a[0], a[1], a[2], a[3]);
  *(float4*)&part[kg][tc*8 + 4] = make_float4(a[4], a[5], a[6], a[7]);
  __syncthreads();
  float s = 0.f;
#pragma unroll
  for (int g = 0; g < 8; ++g) s += part[g][t];
  qk2[row*256 + t] = s * 0.0625f;
}

// ---------------- FUSED attn: NO cross-block atomics (round-11 proven) -----
__global__ __launch_bounds__(256)
void k_attn_up(const u16* __restrict__ xbf, const float* __restrict__ qg,
               float* __restrict__ upart, float* __restrict__ cpart) {
  __shared__ __align__(16) u16 vfL[64][256];
  __shared__ __align__(16) u16 qTL[16][264];
  __shared__ __align__(16) u16 PTL[16][72];
  __shared__ float Lg[64][17];
  __shared__ float csw[4][12];
  int t = threadIdx.x;
  int b = blockIdx.y;
  int bx = blockIdx.x;
  int nb0 = bx * 256;
  int lane = t & 63, w = t >> 6;
  int fr = lane & 15, kq = lane >> 4;

#pragma unroll
  for (int i = t; i < 512; i += 256) {
    int s = i >> 5, k0 = (i & 31) * 8;
    u16x8 o;
    if (s < 11) {
      const float* qp = qg + (size_t)b*2816 + s*256 + k0;
#pragma unroll
      for (int j = 0; j < 8; ++j) o[j] = f2bf(qp[j]);
    } else {
#pragma unroll
      for (int j = 0; j < 8; ++j) o[j] = 0;
    }
    *(u16x8*)&qTL[s][k0] = o;
  }
  for (int i = t; i < 16*72; i += 256) ((u16*)PTL)[i] = 0;

  f32x4 accU[4] = {};
  float cs0 = 0.f, cs1 = 0.f, cs2 = 0.f;
  int rS = t >> 2, g4 = t & 3;
  int j32  = t & 31;              // 16B slot index within a row
  int nsub = t >> 5;              // == n&7 for the rows this thread fills
  int js   = (j32 ^ nsub) * 8;    // swizzled u16 column
  int hc   = j32 * 8;

  for (int c = 0; c < 4; ++c) {
    int n0 = nb0 + c*64;
    __syncthreads();
    {
#pragma unroll
      for (int nr = 0; nr < 8; ++nr) {
        int n = nr*8 + nsub;
        size_t base = ((size_t)b*4096 + n0 + n) * 256;
        u16x8 kvk = *(const u16x8*)(xbf + base + hc);
        *(u16x8*)&vfL[n][js] = kvk;
      }
    }
    __syncthreads();
    {
      f32x4 aL = {};
      int n = w*16 + fr;
#pragma unroll
      for (int kc = 0; kc < 256; kc += 32) {
        bf16x8 af = *(const bf16x8*)&vfL[n][((kc/8 + kq) ^ (fr & 7)) * 8];
        bf16x8 bq = *(const bf16x8*)&qTL[fr][kc + kq*8];
        aL = __builtin_amdgcn_mfma_f32_16x16x32_bf16(af, bq, aL, 0, 0, 0);
      }
#pragma unroll
      for (int r = 0; r < 4; ++r)
        Lg[w*16 + kq*4 + r][fr] = aL[r];
    }
    __syncthreads();
    { // wave-parallel softmax: 4 threads per row, slots split 4+4+3
      float p0 = Lg[rS][g4];
      float p1 = Lg[rS][g4 + 4];
      float p2 = (g4 < 3) ? Lg[rS][g4 + 8] : -1e30f;
      float m = fmaxf(fmaxf(p0, p1), p2);
      m = fmaxf(m, __shfl_xor(m, 1));
      m = fmaxf(m, __shfl_xor(m, 2));
      p0 = __expf(p0 - m); p1 = __expf(p1 - m);
      p2 = (g4 < 3) ? __expf(p2 - m) : 0.f;
      float Z = p0 + p1 + p2;
      Z += __shfl_xor(Z, 1);
      Z += __shfl_xor(Z, 2);
      float iz = 1.f / Z;
      u16 b0 = f2bf(p0*iz + 1e-8f);
      u16 b1 = f2bf(p1*iz + 1e-8f);
      PTL[g4][rS]     = b0;  cs0 += bf2f(b0);
      PTL[g4 + 4][rS] = b1;  cs1 += bf2f(b1);
      if (g4 < 3) {
        u16 b2 = f2bf(p2*iz + 1e-8f);
        PTL[g4 + 8][rS] = b2;  cs2 += bf2f(b2);
      }
    }
    __syncthreads();
#pragma unroll
    for (int ht = 0; ht < 4; ++ht) {
      int h = w*64 + ht*16 + fr;
      int h3 = h >> 3, h7 = h & 7;
#pragma unroll
      for (int kc = 0; kc < 64; kc += 32) {
        bf16x8 aP = *(const bf16x8*)&PTL[fr][kc + kq*8];
        U8cast bv;
#pragma unroll
        for (int j = 0; j < 8; ++j) {
          int k = kc + kq*8 + j;          // k&7 == j
          bv.u[j] = vfL[k][((h3 ^ j) << 3) | h7];
        }
        accU[ht] = __builtin_amdgcn_mfma_f32_16x16x32_bf16(aP, bv.b, accU[ht], 0, 0, 0);
      }
    }
  }
  // ---- epilogue: plain stores of the block's full partial tile ----
  {
    size_t ub = ((size_t)bx*352 + (size_t)b*11) * 256;
#pragma unroll
    for (int ht = 0; ht < 4; ++ht) {
      int h = w*64 + ht*16 + fr;
#pragma unroll
      for (int r = 0; r < 4; ++r) {
        int s = kq*4 + r;
        if (s < 11)
          upart[ub + (size_t)s*256 + h] = accU[ht][r];
      }
    }
  }
  { // block colsum: intra-wave butterfly, cross-wave LDS reduce, one store
#pragma unroll
    for (int off = 4; off < 64; off <<= 1) {
      cs0 += __shfl_xor(cs0, off);
      cs1 += __shfl_xor(cs1, off);
      cs2 += __shfl_xor(cs2, off);
    }
    if (lane < 4) { csw[w][lane] = cs0; csw[w][lane + 4] = cs1; }
    if (lane < 3) { csw[w][lane + 8] = cs2; }
    __syncthreads();
    if (t < 11)
      cpart[(size_t)bx*512 + b*16 + t] =
          csw[0][t] + csw[1][t] + csw[2][t] + csw[3][t];
  }
}

// ---------------- gx = (SUM_p upart / SUM_p cpart) @ Wvi -------------------
__global__ __launch_bounds__(384)
void k_gx(const float* __restrict__ upart, const float* __restrict__ cpart,
          const u16* __restrict__ wvib, float* __restrict__ gx) {
  __shared__ float xn[256];
  __shared__ float part[4][768];
  __shared__ float red16[16];
  int row = blockIdx.x, t = threadIdx.x;
  if (t < 16) red16[t] = cpart[(size_t)t*512 + (row/11)*16 + (row%11)];
  __syncthreads();
  if (t < 256) {
    float cs = 0.f;
#pragma unroll
    for (int p = 0; p < 16; ++p) cs += red16[p];
    float s = 0.f;
#pragma unroll
    for (int p = 0; p < 16; ++p) s += upart[((size_t)p*352 + row)*256 + t];
    xn[t] = s / cs;
  }
  __syncthreads();
  int tc = t % 96, kg = t / 96;
  float a[8] = {};
#pragma unroll 4
  for (int kk = 0; kk < 64; ++kk) {
    int k = kg*64 + kk;
    float xv = xn[k];
    u16x8 wv = *(const u16x8*)(wvib + k*768 + tc*8);
#pragma unroll
    for (int j = 0; j < 8; ++j) a[j] += xv * bf2f(wv[j]);
  }
  *(float4*)&part[kg][tc*8]     = make_float4(a[0], a[1], a[2], a[3]);
  *(float4*)&part[kg][tc*8 + 4] = make_float4(a[4], a[5], a[6], a[7]);
  __syncthreads();
#pragma unroll
  for (int c = t; c < 768; c += 384) {
    float s = part[0][c] + part[1][c] + part[2][c] + part[3][c];
    gx[row*768 + c] = s;
  }
}

// ---------------- GRU (round-6 proven body, do not restructure) ------------
__global__ __launch_bounds__(512)
void k_gru(const float* __restrict__ gx, const u16* __restrict__ whb,
           const float* __restrict__ gb, float* __restrict__ slots) {
  __shared__ float h[256], rh[256], zv[256];
  __shared__ float part[4096];
  int b = blockIdx.x, t = threadIdx.x;
  if (t < 256) h[t] = 0.f;
  __syncthreads();
  for (int step = 0; step < 11; ++step) {
    int row = b*11 + step;
    {
      int tc = t & 63, kg = t >> 6;
      float a[8] = {};
#pragma unroll 8
      for (int kk = 0; kk < 32; ++kk) {
        int k = kg*32 + kk;
        float xv = h[k];
        u16x8 wv = *(const u16x8*)(whb + k*768 + tc*8);
#pragma unroll
        for (int j = 0; j < 8; ++j) a[j] += xv * bf2f(wv[j]);
      }
      *(float4*)&part[kg*512 + tc*8]     = make_float4(a[0], a[1], a[2], a[3]);
      *(float4*)&part[kg*512 + tc*8 + 4] = make_float4(a[4], a[5], a[6], a[7]);
    }
    __syncthreads();
    {
      int c = t;
      float s = gx[row*768 + c] + gb[c];
#pragma unroll
      for (int g = 0; g < 8; ++g) s += part[g*512 + c];
      float sg = 1.f / (1.f + __expf(-s));
      if (c < 256) zv[c] = sg;
      else         rh[c - 256] = sg * h[c - 256];
    }
    __syncthreads();
    {
      int tc = t & 31, kg = t >> 5;
      float a[8] = {};
#pragma unroll 8
      for (int kk = 0; kk < 16; ++kk) {
        int k = kg*16 + kk;
        float xv = rh[k];
        u16x8 wv = *(const u16x8*)(whb + k*768 + 512 + tc*8);
#pragma unroll
        for (int j = 0; j < 8; ++j) a[j] += xv * bf2f(wv[j]);
      }
      *(float4*)&part[kg*256 + tc*8]     = make_float4(a[0], a[1], a[2], a[3]);
      *(float4*)&part[kg*256 + tc*8 + 4] = make_float4(a[4], a[5], a[6], a[7]);
    }
    __syncthreads();
    if (t < 256) {
      int c = t;
      float s = gx[row*768 + 512 + c] + gb[512 + c];
#pragma unroll
      for (int g = 0; g < 16; ++g) s += part[g*256 + c];
      float av = tanhf(s);
      float hn = (1.f - zv[c])*h[c] + zv[c]*av;
      h[c] = hn;
      slots[row*256 + c] = hn;
    }
    __syncthreads();
  }
}

// ---------------- MLP + fused next-iter q_ln (round-8 proven) --------------
__global__ __launch_bounds__(256)
void k_mlp(float* __restrict__ slots, const float* __restrict__ sc,
           const float* __restrict__ of, const u16* __restrict__ w1b,
           const float* __restrict__ b1, const u16* __restrict__ w2b,
           const float* __restrict__ b2,
           const float* __restrict__ sls_, const float* __restrict__ slo,
           const u16* __restrict__ Mb, float* __restrict__ qk2,
           float* __restrict__ out2) {
  __shared__ float xn[256];
  __shared__ float hid[512];
  __shared__ float red[8];
  __shared__ float part[2048];
  int row = blockIdx.x, t = threadIdx.x;
  float v = slots[row*256 + t];
  float s1 = v, s2 = v*v;
#pragma unroll
  for (int off = 32; off; off >>= 1) { s1 += __shfl_xor(s1, off); s2 += __shfl_xor(s2, off); }
  int w = t >> 6;
  if ((t & 63) == 0) { red[w*2] = s1; red[w*2+1] = s2; }
  __syncthreads();
  float a1s = red[0] + red[2] + red[4] + red[6];
  float a2s = red[1] + red[3] + red[5] + red[7];
  float mu = a1s * (1.f/256.f);
  float rs = rsqrtf(a2s * (1.f/256.f) - mu*mu + 1e-5f);
  xn[t] = (v - mu) * rs * sc[t] + of[t];
  __syncthreads();
  {
    int tc = t & 63, kg = t >> 6;
    float a[8] = {};
#pragma unroll 4
    for (int kk = 0; kk < 64; ++kk) {
      int k = kg*64 + kk;
      float xv = xn[k];
      u16x8 wv = *(const u16x8*)(w1b + k*512 + tc*8);
#pragma unroll
      for (int j = 0; j < 8; ++j) a[j] += xv * bf2f(wv[j]);
    }
    *(float4*)&part[kg*512 + tc*8]     = make_float4(a[0], a[1], a[2], a[3]);
    *(float4*)&part[kg*512 + tc*8 + 4] = make_float4(a[4], a[5], a[6], a[7]);
  }
  __syncthreads();
#pragma unroll
  for (int c = t; c < 512; c += 256) {
    float s = b1[c];
#pragma unroll
    for (int g = 0; g < 4; ++g) s += part[g*512 + c];
    hid[c] = fmaxf(s, 0.f);
  }
  __syncthreads();
  {
    int tc = t & 31, kg = t >> 5;
    float a[8] = {};
#pragma unroll 4
    for (int kk = 0; kk < 64; ++kk) {
      int k = kg*64 + kk;
      float xv = hid[k];
      u16x8 wv = *(const u16x8*)(w2b + k*256 + tc*8);
#pragma unroll
      for (int j = 0; j < 8; ++j) a[j] += xv * bf2f(wv[j]);
    }
    *(float4*)&part[kg*256 + tc*8]     = make_float4(a[0], a[1], a[2], a[3]);
    *(float4*)&part[kg*256 + tc*8 + 4] = make_float4(a[4], a[5], a[6], a[7]);
  }
  __syncthreads();
  float snew;
  {
    float s = v + b2[t];
#pragma unroll
    for (int g = 0; g < 8; ++g) s += part[g*256 + t];
    snew = s;
    slots[row*256 + t] = snew;
    if (out2) out2[row*256 + t] = snew;
  }
  if (!qk2) return;
  // fused q_ln: qk2 = LN_slots(snew) @ Mb * H^-0.5
  float q1 = snew, q2 = snew*snew;
#pragma unroll
  for (int off = 32; off; off >>= 1) { q1 += __shfl_xor(q1, off); q2 += __shfl_xor(q2, off); }
  __syncthreads();                       // all prior red/part reads complete
  if ((t & 63) == 0) { red[w*2] = q1; red[w*2+1] = q2; }
  __syncthreads();
  {
    float b1v = red[0] + red[2] + red[4] + red[6];
    float b2v = red[1] + red[3] + red[5] + red[7];
    float mu2 = b1v * (1.f/256.f);
    float rs2 = rsqrtf(b2v * (1.f/256.f) - mu2*mu2 + 1e-5f);
    xn[t] = (snew - mu2) * rs2 * sls_[t] + slo[t];
  }
  __syncthreads();
  {
    int tc = t & 31, kg = t >> 5;
    float a[8] = {};
#pragma unroll 8
    for (int kk = 0; kk < 32; ++kk) {
      int k = kg*32 + kk;
      float xv = xn[k];
      u16x8 wv = *(const u16x8*)(Mb + k*256 + tc*8);
#pragma unroll
      for (int j = 0; j < 8; ++j) a[j] += xv * bf2f(wv[j]);
    }
    *(float4*)&part[kg*256 + tc*8]     = make_float4(a[0], a[1], a[2], a[3]);
    *(float4*)&part[kg*256 + tc*8 + 4] = make_float4(a[4], a[5], a[6], a[7]);
  }
  __syncthreads();
  {
    float s = 0.f;
#pragma unroll
    for (int g = 0; g < 8; ++g) s += part[g*256 + t];
    qk2[row*256 + t] = s * 0.0625f;
  }
}

extern "C" void kernel_launch(void* const* d_in, const int* in_sizes, int n_in,
                              void* d_out, int out_size, void* d_ws, size_t ws_size,
                              hipStream_t stream) {
  (void)in_sizes; (void)n_in; (void)out_size; (void)ws_size;
  const float* inputs = (const float*)d_in[0];
  const float* noise  = (const float*)d_in[1];
  const float* lnin_s = (const float*)d_in[2];
  const float* lnin_o = (const float*)d_in[3];
  const float* lnsl_s = (const float*)d_in[4];
  const float* lnsl_o = (const float*)d_in[5];
  const float* lnml_s = (const float*)d_in[6];
  const float* lnml_o = (const float*)d_in[7];
  const float* smu    = (const float*)d_in[8];
  const float* sls    = (const float*)d_in[9];
  const float* Wq     = (const float*)d_in[10];
  const float* Wk     = (const float*)d_in[11];
  const float* Wv     = (const float*)d_in[12];
  const float* gwi    = (const float*)d_in[13];
  const float* gwh    = (const float*)d_in[14];
  const float* gb     = (const float*)d_in[15];
  const float* w1     = (const float*)d_in[16];
  const float* b1     = (const float*)d_in[17];
  const float* w2     = (const float*)d_in[18];
  const float* b2     = (const float*)d_in[19];

  // ---- workspace layout (512 MiB arena). High-water ~216.2 MB. ------------
  char* ws = (char*)d_ws;
  u16*    wT      = (u16*)(ws + 134217728);              // 131,072 B (Wk^T bf16)
  float*  qk2     = (float*)(ws + 135000064);            // 360,448 B
  float*  slots   = (float*)(ws + 139984896);            // 360,448 B
  float*  gx      = (float*)(ws + 140705792);            // 1,081,344 B
  u16*    Mb      = (u16*)(ws + 141789184);              // 131,072 B (Wq@Wk^T bf16)
  u16*    wvib    = (u16*)(ws + 141920256);              // 393,216 B (Wv@gru_wi bf16)
  u16*    whb     = (u16*)(ws + 142313472);
  u16*    w1b     = (u16*)(ws + 142706688);
  u16*    w2b     = (u16*)(ws + 142968832);
  u16*    xbf     = (u16*)(ws + 143230976);              // 67,108,864 B normalized bf16 x
  float*  upart   = (float*)(ws + 210339840);            // 5,767,168 B [16][352][256]
  float*  cpart   = (float*)(ws + 216107008);            // 32,768 B   [16][512]

  k_stats_ln <<<32768, 256, 0, stream>>>(inputs, lnin_s, lnin_o, xbf);
  k_cvt_w    <<<16,    256, 0, stream>>>(Wk, wT);
  k_mk       <<<256,   256, 0, stream>>>(Wq, wT, Mb);
  k_wvi      <<<256,   384, 0, stream>>>(Wv, gwi, wvib);
  k_cvt_all  <<<2144,  256, 0, stream>>>(gwh, w1, w2, noise, smu, sls,
                                         whb, w1b, w2b, slots);
  k_q_ln     <<<352,   256, 0, stream>>>(slots, lnsl_s, lnsl_o, Mb, qk2);

  for (int it = 0; it < 3; ++it) {
    k_attn_up <<<dim3(16, 32), 256, 0, stream>>>(xbf, qk2, upart, cpart);
    k_gx      <<<352, 384, 0, stream>>>(upart, cpart, wvib, gx);
    k_gru     <<<32,  512, 0, stream>>>(gx, whb, gb, slots);
    k_mlp     <<<352, 256, 0, stream>>>(slots, lnml_s, lnml_o, w1b, b1, w2b, b2,
                                        lnsl_s, lnsl_o, Mb,
                                        (it < 2) ? qk2 : nullptr,
                                        (it == 2) ? (float*)d_out : nullptr);
  }
}